// Round 7
// baseline (466.771 us; speedup 1.0000x reference)
//
#include <hip/hip_runtime.h>
#include <stdint.h>

#define FP8_MAX 448.0f

typedef float floatx16 __attribute__((ext_vector_type(16)));
typedef int   intx4    __attribute__((ext_vector_type(4)));
typedef int   intx8    __attribute__((ext_vector_type(8)));

// ---- fused fp8 e4m3 quantization of x (scaled) and w (unscaled) into ----
// ---- MFMA-fragment-native layout, 16 elem/thread, 16B stores ----
// Layout (per matrix, rows R x cols K): fragment (rblk=m>>5, kstep=k>>6) is
// one contiguous 2048B block at frag = rblk*(K>>6) + kstep; byte (m,k) at
//   frag*2048 + lane*32 + (k&31),  lane = (m&31) | (((k>>5)&1)<<5)
// Each thread quantizes 16 CONSECUTIVE k of one row -> exactly one aligned
// 16B half of one lane's 32B block -> single int4 store (round-6's 4B
// scattered stores cost ~16us of quant time).
__global__ void __launch_bounds__(256) quant_fp8_frag_kernel(
    const float* __restrict__ x, const float* __restrict__ w,
    const float* __restrict__ scale,
    uint8_t* __restrict__ qx, uint8_t* __restrict__ qw,
    long nx16, long ntot16, int K, int kshift)
{
    const float invx = 1.0f / scale[0];
    const int rowFrags = K >> 6;
    const long stride = (long)gridDim.x * 256;
    for (long g = (long)blockIdx.x * 256 + threadIdx.x; g < ntot16; g += stride) {
        const float4* src; uint8_t* dst; float inv; long idx;
        if (g < nx16) { src = (const float4*)x; dst = qx; inv = invx; idx = g; }
        else          { src = (const float4*)w; dst = qw; inv = 1.0f; idx = g - nx16; }
        int out[4];
#pragma unroll
        for (int j = 0; j < 4; ++j) {
            float4 v = src[idx * 4 + j];
            float a = fminf(fmaxf(v.x * inv, -FP8_MAX), FP8_MAX);
            float b = fminf(fmaxf(v.y * inv, -FP8_MAX), FP8_MAX);
            float c = fminf(fmaxf(v.z * inv, -FP8_MAX), FP8_MAX);
            float d = fminf(fmaxf(v.w * inv, -FP8_MAX), FP8_MAX);
            int pk = 0;
            pk = __builtin_amdgcn_cvt_pk_fp8_f32(a, b, pk, false);  // bytes 0..1
            pk = __builtin_amdgcn_cvt_pk_fp8_f32(c, d, pk, true);   // bytes 2..3
            out[j] = pk;
        }
        const long e = idx * 16;               // first element (16-aligned in k)
        const int  m = (int)(e >> kshift);     // row
        const int  k = (int)(e & (K - 1));     // col
        const int  frag = (m >> 5) * rowFrags + (k >> 6);
        const int  lane = (m & 31) | (((k >> 5) & 1) << 5);
        *(int4*)(dst + (size_t)frag * 2048 + lane * 32 + (k & 16)) =
            make_int4(out[0], out[1], out[2], out[3]);
    }
}

// ---- fp8 GEMM via MX-scaled MFMA, NO LDS (flatmm), 2 waves/SIMD ----
// A: qx fragment-native [M/32][K/64][2048B], B: qw same [N/32][K/64][2048B]
// C[m][n] = sum_k A[m][k]*B[n][k];  out = C*osc + bias[n]
//
// Round-7: round-6 was latency-bound at 1 wave/SIMD (acc128 + frags96 +
// addr ~276 unified regs > 256; occupancy 10.76% ~= 4 waves/CU; MfmaUtil
// 39% = 137cy compute / ~350cy round-trip). Fix: cap regs at 256/wave via
// __launch_bounds__(256,2) + lean addressing (6 advancing pointer pairs,
// immediate offsets 0/16/2048/2064, += 4096 per 2-step) so TWO waves/SIMD
// co-reside and cover each other's L2 latency with MFMA work.
// Per wave per K-step: 4 A-frags + 2 B-frags (12 dwordx4; each frag = one
// contiguous 2KB block read at lane*32+{0,16}) + 8
// v_mfma_scale_f32_32x32x64_f8f6f4 (unit e8m0 scales = bit-exact fp8).
// Block = 4 waves sharing 128 A-rows (L1-served x4 reuse); wave wid owns
// 64 N-cols. Grid (N/256, M/128): lin%8 = x%8 -> each XCD serves 2 B-panels
// (2MB, L2-resident).
__global__ void __launch_bounds__(256, 2) gemm_fp8_kernel(
    const uint8_t* __restrict__ A, const uint8_t* __restrict__ B,
    const float* __restrict__ bias,
    const float* __restrict__ in_scale, const float* __restrict__ w_scale,
    float* __restrict__ C, int M, int N, int K)
{
    const int tid  = threadIdx.x;
    const int lane = tid & 63;
    const int wid  = tid >> 6;       // 0..3: wave's 64-col slice
    const int m0   = blockIdx.y * 128;
    const int n0   = blockIdx.x * 256;

    const int rl = lane & 31;        // row/col within the 32-block
    const int h  = lane >> 5;        // k-half

    const int rowFrags = K >> 6;
    const int NS = rowFrags;         // K-steps; NS even, >= 4

    // advancing fragment pointers (2048B per K-step; advanced 4096 per unroll)
    const uint8_t* pA[4];
    const uint8_t* pB[2];
#pragma unroll
    for (int mi = 0; mi < 4; ++mi)
        pA[mi] = A + ((size_t)((m0 >> 5) + mi) * rowFrags) * 2048 + lane * 32;
#pragma unroll
    for (int ni = 0; ni < 2; ++ni)
        pB[ni] = B + ((size_t)((n0 >> 5) + wid * 2 + ni) * rowFrags) * 2048 + lane * 32;

    floatx16 acc[4][2];
#pragma unroll
    for (int i = 0; i < 4; ++i)
#pragma unroll
        for (int j = 0; j < 2; ++j)
#pragma unroll
            for (int r = 0; r < 16; ++r) acc[i][j][r] = 0.f;

    const int sOne = 0x7F7F7F7F;  // e8m0 = 127 -> 2^0 = 1.0 in every byte

    auto loadA = [&](intx8* dst, int off) {
#pragma unroll
        for (int mi = 0; mi < 4; ++mi) {
            intx4 lo = *(const intx4*)(pA[mi] + off);
            intx4 hi = *(const intx4*)(pA[mi] + off + 16);
            dst[mi] = (intx8){lo[0], lo[1], lo[2], lo[3],
                              hi[0], hi[1], hi[2], hi[3]};
        }
    };
    auto loadB = [&](intx8* dst, int off) {
#pragma unroll
        for (int ni = 0; ni < 2; ++ni) {
            intx4 lo = *(const intx4*)(pB[ni] + off);
            intx4 hi = *(const intx4*)(pB[ni] + off + 16);
            dst[ni] = (intx8){lo[0], lo[1], lo[2], lo[3],
                              hi[0], hi[1], hi[2], hi[3]};
        }
    };
    auto advance = [&]() {
#pragma unroll
        for (int mi = 0; mi < 4; ++mi) pA[mi] += 4096;
#pragma unroll
        for (int ni = 0; ni < 2; ++ni) pB[ni] += 4096;
    };
    auto mfma8 = [&](intx8* av, intx8* bv) {
        __builtin_amdgcn_s_setprio(1);
#pragma unroll
        for (int mi = 0; mi < 4; ++mi) {
            acc[mi][0] = __builtin_amdgcn_mfma_scale_f32_32x32x64_f8f6f4(
                av[mi], bv[0], acc[mi][0], 0, 0, 0, sOne, 0, sOne);
            acc[mi][1] = __builtin_amdgcn_mfma_scale_f32_32x32x64_f8f6f4(
                av[mi], bv[1], acc[mi][1], 0, 0, 0, sOne, 0, sOne);
        }
        __builtin_amdgcn_s_setprio(0);
    };

    // ping-pong register buffers (named sets -> static indexing, no scratch)
    intx8 a0[4], b0[2], a1[4], b1[2];
    loadA(a0, 0);    loadB(b0, 0);      // step 0
    loadA(a1, 2048); loadB(b1, 2048);   // step 1
    advance();                          // pointers -> step 2

    for (int t = 0; t + 2 < NS; t += 2) {
        mfma8(a0, b0);                  // step t
        loadA(a0, 0);    loadB(b0, 0);       // prefetch t+2
        mfma8(a1, b1);                  // step t+1
        loadA(a1, 2048); loadB(b1, 2048);    // prefetch t+3
        advance();
    }
    mfma8(a0, b0);
    mfma8(a1, b1);

    const float osc = in_scale[0] * w_scale[0];

    // epilogue: 32x32 C/D layout (m74/m101, shape-determined):
    // col = lane&31, row = (reg&3) + 8*(reg>>2) + 4*(lane>>5)
#pragma unroll
    for (int mi = 0; mi < 4; ++mi) {
#pragma unroll
        for (int ni = 0; ni < 2; ++ni) {
            const int gn = n0 + wid * 64 + ni * 32 + rl;
            const float bvv = bias[gn];
#pragma unroll
            for (int r = 0; r < 16; ++r) {
                const int row = (r & 3) + 8 * (r >> 2) + 4 * h;
                const int gm = m0 + mi * 32 + row;
                C[(size_t)gm * N + gn] = acc[mi][ni][r] * osc + bvv;
            }
        }
    }
}

extern "C" void kernel_launch(void* const* d_in, const int* in_sizes, int n_in,
                              void* d_out, int out_size, void* d_ws, size_t ws_size,
                              hipStream_t stream) {
    const float* x        = (const float*)d_in[0];  // [M][K]
    const float* weight   = (const float*)d_in[1];  // [N][K], fp8-grid values
    const float* w_scale  = (const float*)d_in[2];  // [1]
    const float* bias     = (const float*)d_in[3];  // [N]
    const float* in_scale = (const float*)d_in[4];  // [1]
    float* out = (float*)d_out;

    const int N = in_sizes[3];                 // D_OUT = 4096
    const int K = in_sizes[1] / N;             // D_IN  = 4096
    const int M = in_sizes[0] / K;             // N_TOK = 8192

    int kshift = 0; while ((1 << kshift) < K) ++kshift;   // K = 4096 -> 12

    uint8_t* qx = (uint8_t*)d_ws;                          // M*K fp8 (32 MB)
    uint8_t* qw = (uint8_t*)d_ws + (size_t)M * K;          // N*K fp8 (16 MB)

    const long nx16   = (long)M * K / 16;        // 2097152, = 4 * 524288
    const long ntot16 = nx16 + (long)N * K / 16; // + 1048576
    long blks = (ntot16 + 255) / 256; if (blks > 2048) blks = 2048;
    quant_fp8_frag_kernel<<<(int)blks, 256, 0, stream>>>(
        x, weight, in_scale, qx, qw, nx16, ntot16, K, kshift);

    dim3 grid(N / 256, M / 128);  // (16, 64)
    gemm_fp8_kernel<<<grid, 256, 0, stream>>>(qx, qw, bias, in_scale, w_scale,
                                              out, M, N, K);
}

// Round 9
// 419.065 us; speedup vs baseline: 1.1138x; 1.1138x over previous
//
#include <hip/hip_runtime.h>
#include <stdint.h>

#define FP8_MAX 448.0f

typedef float floatx16 __attribute__((ext_vector_type(16)));
typedef int   intx4    __attribute__((ext_vector_type(4)));
typedef int   intx8    __attribute__((ext_vector_type(8)));

// ---- fused fp8 e4m3 quantization of x (scaled) and w (unscaled) into ----
// ---- MFMA-fragment-native layout, 16 elem/thread, 16B stores ----
// Layout (per matrix, rows R x cols K): fragment (rblk=m>>5, kstep=k>>6) is
// one contiguous 2048B block at frag = rblk*(K>>6) + kstep; byte (m,k) at
//   frag*2048 + lane*32 + (k&31),  lane = (m&31) | (((k>>5)&1)<<5)
// Each thread quantizes 16 CONSECUTIVE k of one row -> exactly one aligned
// 16B half of one lane's 32B block -> single int4 store.
__global__ void __launch_bounds__(256) quant_fp8_frag_kernel(
    const float* __restrict__ x, const float* __restrict__ w,
    const float* __restrict__ scale,
    uint8_t* __restrict__ qx, uint8_t* __restrict__ qw,
    long nx16, long ntot16, int K, int kshift)
{
    const float invx = 1.0f / scale[0];
    const int rowFrags = K >> 6;
    const long stride = (long)gridDim.x * 256;
    for (long g = (long)blockIdx.x * 256 + threadIdx.x; g < ntot16; g += stride) {
        const float4* src; uint8_t* dst; float inv; long idx;
        if (g < nx16) { src = (const float4*)x; dst = qx; inv = invx; idx = g; }
        else          { src = (const float4*)w; dst = qw; inv = 1.0f; idx = g - nx16; }
        int out[4];
#pragma unroll
        for (int j = 0; j < 4; ++j) {
            float4 v = src[idx * 4 + j];
            float a = fminf(fmaxf(v.x * inv, -FP8_MAX), FP8_MAX);
            float b = fminf(fmaxf(v.y * inv, -FP8_MAX), FP8_MAX);
            float c = fminf(fmaxf(v.z * inv, -FP8_MAX), FP8_MAX);
            float d = fminf(fmaxf(v.w * inv, -FP8_MAX), FP8_MAX);
            int pk = 0;
            pk = __builtin_amdgcn_cvt_pk_fp8_f32(a, b, pk, false);  // bytes 0..1
            pk = __builtin_amdgcn_cvt_pk_fp8_f32(c, d, pk, true);   // bytes 2..3
            out[j] = pk;
        }
        const long e = idx * 16;               // first element (16-aligned in k)
        const int  m = (int)(e >> kshift);     // row
        const int  k = (int)(e & (K - 1));     // col
        const int  frag = (m >> 5) * rowFrags + (k >> 6);
        const int  lane = (m & 31) | (((k >> 5) & 1) << 5);
        *(int4*)(dst + (size_t)frag * 2048 + lane * 32 + (k & 16)) =
            make_int4(out[0], out[1], out[2], out[3]);
    }
}

// ---- fp8 GEMM via MX-scaled MFMA, NO LDS (flatmm), 2 waves/SIMD ----
// A: qx fragment-native [M/32][K/64][2048B], B: qw same [N/32][K/64][2048B]
// C[m][n] = sum_k A[m][k]*B[n][k];  out = C*osc + bias[n]
//
// Round-8/9 model (locked by r6/r7 counters): mfma pipe is per-SIMD; one
// mfma_scale_32x32x64 ~= 69 SIMD-cyc, so a step (8 mfma) = 550 cyc busy.
// r6 measured 1418 cyc/step -> MfmaUtil 550/1418 = 38.8% (matches 39.4):
// 1 wave/SIMD exposing ~870cyc of L2/L3 latency. r7 tried 2 waves/SIMD
// but spilled (VGPR 128 + AGPR cap; WRITE_SIZE +39MB scratch in-loop).
// Fix: SINGLE-buffered frags (a[4],b[2] = 48 regs) + uniform SGPR frag
// offsets + one per-lane voffset; acc 128 + frags 48 + misc ~= 195 <= 256
// -> 2 waves/SIMD co-reside spill-free, covering each other's load
// latency (duty ~ 2x550/(550+lat)).
// Per wave per step: 4 A-frags + 2 B-frags (12 dwordx4, each frag = one
// contiguous 2KB block at lane*32+{0,16}) + 8 mfma (unit e8m0 scales =
// bit-exact plain fp8). Block = 4 waves sharing 128 A-rows (L1 x4 reuse);
// wave wid owns 64 N-cols. Grid (N/256, M/128): lin%8 = x%8 -> 2 B-panels
// (2MB) per XCD, L2-resident.
__global__ void __launch_bounds__(256, 2) gemm_fp8_kernel(
    const uint8_t* __restrict__ A, const uint8_t* __restrict__ B,
    const float* __restrict__ bias,
    const float* __restrict__ in_scale, const float* __restrict__ w_scale,
    float* __restrict__ C, int M, int N, int K)
{
    const int tid  = threadIdx.x;
    const int lane = tid & 63;
    const int wid  = tid >> 6;       // 0..3: wave's 64-col slice
    const int m0   = blockIdx.y * 128;
    const int n0   = blockIdx.x * 256;

    const int rl = lane & 31;        // row/col within the 32-block
    const int h  = lane >> 5;        // k-half

    const int rowFrags = K >> 6;
    const int NS = rowFrags;         // K-steps

    // uniform (SGPR) bases; per-lane part is a single voffset (lane*32)
    const size_t panel = (size_t)rowFrags * 2048;   // bytes per 32-row panel
    const uint8_t* baseA = A + (size_t)(m0 >> 5) * panel + lane * 32;
    const uint8_t* baseB = B + (size_t)((n0 >> 5) + wid * 2) * panel + lane * 32;

    floatx16 acc[4][2];
#pragma unroll
    for (int i = 0; i < 4; ++i)
#pragma unroll
        for (int j = 0; j < 2; ++j)
#pragma unroll
            for (int r = 0; r < 16; ++r) acc[i][j][r] = 0.f;

    const int sOne = 0x7F7F7F7F;  // e8m0 = 127 -> 2^0 = 1.0 in every byte

    for (int t = 0; t < NS; ++t) {
        const size_t kb = (size_t)t * 2048;
        intx8 a[4], b[2];
#pragma unroll
        for (int mi = 0; mi < 4; ++mi) {
            const uint8_t* p = baseA + mi * panel + kb;
            intx4 lo = *(const intx4*)(p);
            intx4 hi = *(const intx4*)(p + 16);
            a[mi] = (intx8){lo[0], lo[1], lo[2], lo[3],
                            hi[0], hi[1], hi[2], hi[3]};
        }
#pragma unroll
        for (int ni = 0; ni < 2; ++ni) {
            const uint8_t* p = baseB + ni * panel + kb;
            intx4 lo = *(const intx4*)(p);
            intx4 hi = *(const intx4*)(p + 16);
            b[ni] = (intx8){lo[0], lo[1], lo[2], lo[3],
                            hi[0], hi[1], hi[2], hi[3]};
        }

        __builtin_amdgcn_s_setprio(1);
#pragma unroll
        for (int mi = 0; mi < 4; ++mi) {
            acc[mi][0] = __builtin_amdgcn_mfma_scale_f32_32x32x64_f8f6f4(
                a[mi], b[0], acc[mi][0], 0, 0, 0, sOne, 0, sOne);
            acc[mi][1] = __builtin_amdgcn_mfma_scale_f32_32x32x64_f8f6f4(
                a[mi], b[1], acc[mi][1], 0, 0, 0, sOne, 0, sOne);
        }
        __builtin_amdgcn_s_setprio(0);
    }

    const float osc = in_scale[0] * w_scale[0];

    // epilogue: 32x32 C/D layout (m74/m101, shape-determined):
    // col = lane&31, row = (reg&3) + 8*(reg>>2) + 4*(lane>>5)
#pragma unroll
    for (int mi = 0; mi < 4; ++mi) {
#pragma unroll
        for (int ni = 0; ni < 2; ++ni) {
            const int gn = n0 + wid * 64 + ni * 32 + rl;
            const float bvv = bias[gn];
#pragma unroll
            for (int r = 0; r < 16; ++r) {
                const int row = (r & 3) + 8 * (r >> 2) + 4 * h;
                const int gm = m0 + mi * 32 + row;
                C[(size_t)gm * N + gn] = acc[mi][ni][r] * osc + bvv;
            }
        }
    }
}

extern "C" void kernel_launch(void* const* d_in, const int* in_sizes, int n_in,
                              void* d_out, int out_size, void* d_ws, size_t ws_size,
                              hipStream_t stream) {
    const float* x        = (const float*)d_in[0];  // [M][K]
    const float* weight   = (const float*)d_in[1];  // [N][K], fp8-grid values
    const float* w_scale  = (const float*)d_in[2];  // [1]
    const float* bias     = (const float*)d_in[3];  // [N]
    const float* in_scale = (const float*)d_in[4];  // [1]
    float* out = (float*)d_out;

    const int N = in_sizes[3];                 // D_OUT = 4096
    const int K = in_sizes[1] / N;             // D_IN  = 4096
    const int M = in_sizes[0] / K;             // N_TOK = 8192

    int kshift = 0; while ((1 << kshift) < K) ++kshift;   // K = 4096 -> 12

    uint8_t* qx = (uint8_t*)d_ws;                          // M*K fp8 (32 MB)
    uint8_t* qw = (uint8_t*)d_ws + (size_t)M * K;          // N*K fp8 (16 MB)

    const long nx16   = (long)M * K / 16;        // 2097152, = 4 * 524288
    const long ntot16 = nx16 + (long)N * K / 16; // + 1048576
    long blks = (ntot16 + 255) / 256; if (blks > 2048) blks = 2048;
    quant_fp8_frag_kernel<<<(int)blks, 256, 0, stream>>>(
        x, weight, in_scale, qx, qw, nx16, ntot16, K, kshift);

    dim3 grid(N / 256, M / 128);  // (16, 64)
    gemm_fp8_kernel<<<grid, 256, 0, stream>>>(qx, qw, bias, in_scale, w_scale,
                                              out, M, N, K);
}